// Round 10
// baseline (292.586 us; speedup 1.0000x reference)
//
#include <hip/hip_runtime.h>
#include <stdint.h>

// Calibration-histogram kernel for MI355X (round 8).
// probs: (1,2,4096,4096) f32, labels: (1,1,4096,4096) i32.
// Outputs (flat, 90 f32): count0[15], csum0[15], asum0[15], count1[15], csum1[15], asum1[15].
//
// Round-7 post-mortem: latency-bound (occ 17%, VALU 17%, HBM 13%, 0 conflicts).
// Cause: 64KB LDS (2 blocks/CU) + one serial may-alias chain of 8 u64 RMWs/iter.
// Fixes: (1) u32 packed accumulator (count[6:0] | asum[13:7] | csum[31:14],
// fixed-point 2^11) -> 32KB LDS, 4-5 blocks/CU; (2) ch0/ch1 in DISTINCT
// __shared__ arrays -> provable NoAlias -> 2 independent chains of 4;
// (3) 1024 blocks x 16 iters/thread (count<=68<128, csum<=139264<2^18 ok);
// (4) manual next-iter prefetch; (5) all-256-thread merge with 8-lane shfl.

#define NBINS 15

__global__ void zero_out_kernel(float* out, int n) {
    int i = blockIdx.x * blockDim.x + threadIdx.x;
    if (i < n) out[i] = 0.0f;
}

__device__ __forceinline__ unsigned pack_u32(float c, int match, int* bin_out) {
    // Reference: bin i holds conf in (b[i], b[i+1]]; conf==0 -> invalid.
    bool valid = (c > 0.0f) && (c <= 1.0f);
    float cb = fmaxf(fminf(c * 15.0f, 14.0f), 0.0f);   // clamped bin, branchless
    *bin_out = (int)cb;
    unsigned cf = __float2uint_rn(fmaxf(c, 0.0f) * 2048.0f);  // conf * 2^11
    unsigned v = (cf << 14) | ((match ? 1u : 0u) << 7) | 1u;
    return valid ? v : 0u;   // invalid -> add zero, uniform control flow
}

__global__ __launch_bounds__(256, 4) void calib_hist_kernel(
        const float* __restrict__ probs, const int* __restrict__ labels,
        float* __restrict__ out, int npix) {
    // Per-LANE private histograms; ch0 and ch1 in distinct arrays so the
    // compiler proves NoAlias between their RMW chains (ILP x2).
    // bank(word = bin*256 + tid) = tid mod 32 -> bin-independent, conflict-free.
    __shared__ unsigned histA[16 * 256];   // ch0, 16 KB
    __shared__ unsigned histB[16 * 256];   // ch1, 16 KB
    int tid = threadIdx.x;
    #pragma unroll
    for (int k = 0; k < 16; ++k) {
        histA[k * 256 + tid] = 0u;
        histB[k * 256 + tid] = 0u;
    }
    __syncthreads();

    const float4* p0 = (const float4*)probs;           // channel 0
    const float4* p1 = (const float4*)(probs + npix);  // channel 1
    const int4*   lb = (const int4*)labels;
    int nvec   = npix >> 2;
    int stride = gridDim.x * blockDim.x;

    int i = blockIdx.x * blockDim.x + tid;
    if (i < nvec) {
        float4 a = p0[i], b = p1[i];
        int4   l = lb[i];
        while (true) {
            int  ni   = i + stride;
            bool more = ni < nvec;
            float4 a2, b2; int4 l2;
            if (more) { a2 = p0[ni]; b2 = p1[ni]; l2 = lb[ni]; }  // prefetch
            int bin; unsigned v;
            // Two independent non-atomic RMW chains (histA vs histB NoAlias).
            v = pack_u32(a.x, l.x == 0, &bin); histA[bin * 256 + tid] += v;
            v = pack_u32(b.x, l.x == 1, &bin); histB[bin * 256 + tid] += v;
            v = pack_u32(a.y, l.y == 0, &bin); histA[bin * 256 + tid] += v;
            v = pack_u32(b.y, l.y == 1, &bin); histB[bin * 256 + tid] += v;
            v = pack_u32(a.z, l.z == 0, &bin); histA[bin * 256 + tid] += v;
            v = pack_u32(b.z, l.z == 1, &bin); histB[bin * 256 + tid] += v;
            v = pack_u32(a.w, l.w == 0, &bin); histA[bin * 256 + tid] += v;
            v = pack_u32(b.w, l.w == 1, &bin); histB[bin * 256 + tid] += v;
            if (!more) break;
            i = ni; a = a2; b = b2; l = l2;
        }
    }
    __syncthreads();

    // Merge with all 256 threads: thread h owns entry e = h>>3
    // (ch = e>>4, bin = e&15) and column chunk (h&7)*32, rotated by h:
    // bank = (j+h)&31 -> 2 lanes/bank (free). Unpack BEFORE summing
    // (packed fields would overflow). Then 8-lane shfl_xor reduce.
    {
        int h   = tid;
        int e   = h >> 3, ch = e >> 4, bin = e & 15;
        const unsigned* src = ch ? histB : histA;
        unsigned cnt = 0, asum = 0, csum = 0;
        int base = (h & 7) * 32;
        #pragma unroll
        for (int j = 0; j < 32; ++j) {
            int col = base + ((j + h) & 31);
            unsigned x = src[bin * 256 + col];
            cnt  += x & 0x7Fu;
            asum += (x >> 7) & 0x7Fu;
            csum += x >> 14;
        }
        cnt  += __shfl_xor(cnt, 1); asum += __shfl_xor(asum, 1); csum += __shfl_xor(csum, 1);
        cnt  += __shfl_xor(cnt, 2); asum += __shfl_xor(asum, 2); csum += __shfl_xor(csum, 2);
        cnt  += __shfl_xor(cnt, 4); asum += __shfl_xor(asum, 4); csum += __shfl_xor(csum, 4);
        if ((h & 7) == 0 && bin < NBINS) {
            float* obase = out + ch * 45;
            atomicAdd(obase + bin,               (float)cnt);
            atomicAdd(obase + NBINS + bin,       (float)csum * (1.0f / 2048.0f));
            atomicAdd(obase + 2 * NBINS + bin,   (float)asum);
        }
    }
}

extern "C" void kernel_launch(void* const* d_in, const int* in_sizes, int n_in,
                              void* d_out, int out_size, void* d_ws, size_t ws_size,
                              hipStream_t stream) {
    const float* probs  = (const float*)d_in[0];
    const int*   labels = (const int*)d_in[1];
    float*       out    = (float*)d_out;
    int npix = in_sizes[1];  // 4096*4096 pixels; probs has 2*npix elements

    zero_out_kernel<<<(out_size + 127) / 128, 128, 0, stream>>>(out, out_size);

    // 16 iters/thread cap keeps packed fields carry-safe (count<=68<128).
    // 1024 blocks, 32KB LDS -> 4-5 blocks/CU resident, ~16-20 waves/CU.
    int nvec = npix >> 2;
    int blocks = (nvec + 256 * 16 - 1) / (256 * 16);
    if (blocks < 1) blocks = 1;
    calib_hist_kernel<<<blocks, 256, 0, stream>>>(probs, labels, out, npix);
}